// Round 5
// baseline (121.939 us; speedup 1.0000x reference)
//
#include <hip/hip_runtime.h>

// BatchIndependentLoss: SupCon-style loss, B=2048, V=2, D=256, N=4096.
// loss = -mean_i( lp_i - (W_i - e^{lp}*lp) / u_new[i%B] )
// R13: occupancy x latency attack on gemm (the only attackable term).
// Window decomposition (stable over R10-R12): ~88us harness-fixed
// (256MiB fill ~41us + restores + graph gaps) + ~23us ours
// (prep ~3, gemm ~15, finalize ~1, boundaries ~4). gemm's throughput
// floor is ~3us => latency-bound at 2 waves/SIMD (VGPR ~185).
// Change vs R12: half-tile gemm (32-row x 64-col, 4160 single-wave
// blocks) WITH depth-2 prefetch. R11 proved the half-tile structure is
// cheap (VGPR=48 depth-1); its 340us was purely the per-block agent
// __threadfence L2 flush (removed). Budget: acc 32 + 3 rotating bufs
// x 6 frags x 4 = 72 + addr ~ 120 VGPR -> launch_bounds(64,4) = 4
// waves/SIMD (2x R12) while keeping depth-2's within-wave cover.
// Cost: B-frag L2 traffic 67->100 MB (+~1us), col atomics x2 (+~0.5us).
// Math identical to R9/R12 (unshifted exp2 domain: f=exp2(d*C1), S1+=f,
// S2+=f*d*C1; per-row 2^msd shift in finalize; msd from diagonal tiles).
//
// CmF layout: shorts, index = ((band*8 + k)*4 + rt)*512 + (l15*4+quad)*8 + j
// Fragment load for (band, k, rt): wave reads one contiguous 1 KB chunk.

#define BSZ   2048
#define NROW  4096
#define NB64  64                       // 4096/64 bands
#define NT2   (NB64 * (NB64 + 1) / 2)  // 2080 upper-triangle 64x64 tiles
#define NBLK  (NT2 * 2)                // 4160 half-tile blocks
#define C1    (1.4426950408889634f / 0.07f)   // log2(e)/TEMPERATURE
#define LN2   0.6931471805599453f

typedef __attribute__((ext_vector_type(8))) __bf16 bf16x8;
typedef __attribute__((ext_vector_type(4))) float f32x4;

__device__ __forceinline__ short f2bs(float x) {
    __bf16 b = (__bf16)x;
    return __builtin_bit_cast(short, b);
}

// contrast row i = v*B + b  ->  features row b*V + v  (fp32, 256 elems)
__device__ __forceinline__ const float* crow_ptr(const float* feats, int i) {
    return feats + (((i & (BSZ - 1)) * 2 + (i >> 11)) << 8);
}

// ---- pack one gid unit (8 shorts) of the frag-major bf16 operand ----------
__device__ __forceinline__ void pack_unit(const float* __restrict__ feats,
                                          short* __restrict__ CmF, int gid) {
    int quad = gid & 3;
    int l15  = (gid >> 2) & 15;
    int rt   = (gid >> 6) & 3;
    int k    = (gid >> 8) & 7;
    int b    = gid >> 12;
    int srow = (b << 6) + (rt << 4) + l15;
    int kel  = (k << 5) + (quad << 3);
    const float4* fp = (const float4*)(crow_ptr(feats, srow) + kel);
    float4 v0 = fp[0], v1 = fp[1];
    short h[8] = { f2bs(v0.x), f2bs(v0.y), f2bs(v0.z), f2bs(v0.w),
                   f2bs(v1.x), f2bs(v1.y), f2bs(v1.z), f2bs(v1.w) };
    *(int4*)(CmF + gid * 8) = *(int4*)h;
}

// ---------------- prep: pack + zero S1/S2/out ------------------------------
__global__ __launch_bounds__(256) void prep_kernel(const float* __restrict__ feats,
        float* __restrict__ S1, short* __restrict__ CmF, float* __restrict__ out) {
    int gid = blockIdx.x * 256 + threadIdx.x;    // 0..262143
    if (gid < 2 * NROW) S1[gid] = 0.0f;          // S1 | S2 contiguous
    else if (gid == 2 * NROW) out[0] = 0.0f;
    pack_unit(feats, CmF, gid);
}

// ---------------- barrier-free symmetric GEMM + stats ----------------------
// One 64-thread block == one wave == one 32-row x 64-col half-tile.
// Depth-2 prefetch (3 rotating buffers). Unshifted exp2 domain.
__global__ __launch_bounds__(64, 4) void gemm_sym(const short* __restrict__ CmF,
        float* __restrict__ S1, float* __restrict__ S2,
        float* __restrict__ Praw, float* __restrict__ Draw) {
    int lane = threadIdx.x;          // 0..63
    int quad = lane >> 4;
    int l15  = lane & 15;

    int bh = blockIdx.x;
    int h  = bh & 1;                 // half: frag rows rt in {2h, 2h+1}
    int t  = bh >> 1;
    // triangle decode t -> (p,q), p>=q
    int p = (int)((sqrtf(8.0f * (float)t + 1.0f) - 1.0f) * 0.5f);
    while ((p + 1) * (p + 2) / 2 <= t) ++p;
    while (p * (p + 1) / 2 > t) --p;
    int q = t - p * (p + 1) / 2;
    int rowBase = q << 6;            // row band (64)
    int colBase = p << 6;            // col band, >= row band
    bool offdiag = (p != q);

    int laneOff = ((l15 << 2) + quad) * 8;
    const short* aB = CmF + q * 16384 + laneOff + h * 1024;  // our 2 rt frags
    const short* bB = CmF + p * 16384 + laneOff;

    f32x4 acc[2][4];
    #pragma unroll
    for (int a = 0; a < 2; ++a)
        #pragma unroll
        for (int c = 0; c < 4; ++c) acc[a][c] = (f32x4){0.f, 0.f, 0.f, 0.f};

    // depth-2 software pipeline: 3 rotating fragment buffers
    bf16x8 aF[3][2], bF[3][4];
    #pragma unroll
    for (int s = 0; s < 2; ++s) {
        #pragma unroll
        for (int j = 0; j < 2; ++j)
            aF[s][j] = *(const bf16x8*)(aB + s * 2048 + j * 512);
        #pragma unroll
        for (int ct = 0; ct < 4; ++ct)
            bF[s][ct] = *(const bf16x8*)(bB + s * 2048 + ct * 512);
    }

    #pragma unroll
    for (int k = 0; k < 8; ++k) {
        int cur = k % 3;
        int nxt = (k + 2) % 3;
        if (k < 6) {                 // issue loads for step k+2 (2 ahead)
            #pragma unroll
            for (int j = 0; j < 2; ++j)
                aF[nxt][j] = *(const bf16x8*)(aB + (k + 2) * 2048 + j * 512);
            #pragma unroll
            for (int ct = 0; ct < 4; ++ct)
                bF[nxt][ct] = *(const bf16x8*)(bB + (k + 2) * 2048 + ct * 512);
        }
        __builtin_amdgcn_s_setprio(1);
        #pragma unroll
        for (int j = 0; j < 2; ++j)
            #pragma unroll
            for (int ct = 0; ct < 4; ++ct)
                acc[j][ct] = __builtin_amdgcn_mfma_f32_16x16x32_bf16(
                    aF[cur][j], bF[cur][ct], acc[j][ct], 0, 0, 0);
        __builtin_amdgcn_s_setprio(0);
    }

    // ---- epilogue: C/D layout col = lane&15, row = quad*4 + reg  [m89/m91]
    // Unshifted domain: one exp2 per element, feeds BOTH row and col sums.
    float S1r[2][4] = {}, S2r[2][4] = {};
    float S1c[4] = {}, S2c[4] = {};
    #pragma unroll
    for (int j = 0; j < 2; ++j) {
        #pragma unroll
        for (int ct = 0; ct < 4; ++ct) {
            #pragma unroll
            for (int r = 0; r < 4; ++r) {
                float d  = acc[j][ct][r];
                float t0 = d * C1;
                float f  = __builtin_exp2f(t0);
                S1r[j][r] += f;
                S2r[j][r] = __builtin_fmaf(f, t0, S2r[j][r]);
                if (offdiag) {
                    S1c[ct] += f;
                    S2c[ct] = __builtin_fmaf(f, t0, S2c[ct]);
                }
            }
        }
    }

    // ---- Praw: only tiles with p == q^32 contain positives (j = i^2048)
    if (p == (q ^ 32) && quad == (l15 >> 2)) {
        int r = l15 & 3;
        #pragma unroll
        for (int j = 0; j < 2; ++j) {
            int rt = 2 * h + j;
            float t0 = acc[j][rt][r] * C1;     // positive sits at ct == rt
            Praw[rowBase + rt * 16 + l15] = t0;
            Praw[colBase + rt * 16 + l15] = t0;
        }
    }
    // ---- Draw: diagonal tiles hold the self-dot (msd = -Draw in finalize)
    if (!offdiag && quad == (l15 >> 2)) {
        int r = l15 & 3;
        #pragma unroll
        for (int j = 0; j < 2; ++j) {
            int rt = 2 * h + j;
            Draw[rowBase + rt * 16 + l15] = acc[j][rt][r] * C1;
        }
    }

    // row-path: reduce over 16 l15 lanes per row, 1-lane atomic per row
    #pragma unroll
    for (int j = 0; j < 2; ++j) {
        #pragma unroll
        for (int r = 0; r < 4; ++r) {
            float e = S1r[j][r], w = S2r[j][r];
            #pragma unroll
            for (int off = 1; off < 16; off <<= 1) {
                e += __shfl_xor(e, off, 64);
                w += __shfl_xor(w, off, 64);
            }
            if (l15 == 0) {
                int grow = rowBase + (2 * h + j) * 16 + (quad << 2) + r;
                atomicAdd(&S1[grow], e);
                atomicAdd(&S2[grow], w);
            }
        }
    }
    // col-path: reduce over 4 quads per col, 16-lane atomic
    if (offdiag) {
        #pragma unroll
        for (int ct = 0; ct < 4; ++ct) {
            float e = S1c[ct], w = S2c[ct];
            e += __shfl_xor(e, 16, 64);  w += __shfl_xor(w, 16, 64);
            e += __shfl_xor(e, 32, 64);  w += __shfl_xor(w, 32, 64);
            if (quad == 0) {
                int gcol = colBase + ct * 16 + l15;
                atomicAdd(&S1[gcol], e);
                atomicAdd(&S2[gcol], w);
            }
        }
    }
}

// ---------------- finalize: 32 blocks x 64, one wave per band-pair ---------
// block b owns rows rlo = b*64+lane (batch elems, view 0) and rhi = rlo+2048
// (view 1). unew is per-lane (same batch elem for both rows). m = -Draw;
// E = 2^m*S1; W = 2^m*(S2 + m*S1); tp = Praw + m.
__global__ __launch_bounds__(64) void finalize_kernel(const int* __restrict__ index,
        const float* __restrict__ u, const float* __restrict__ S1,
        const float* __restrict__ S2, const float* __restrict__ Praw,
        const float* __restrict__ Draw, float* __restrict__ out) {
    int lane = threadIdx.x;
    int rlo  = (blockIdx.x << 6) + lane;   // 0..2047
    int rhi  = rlo + BSZ;                  // 2048..4095

    float mlo = -Draw[rlo], mhi = -Draw[rhi];
    float tplo = Praw[rlo] + mlo, tphi = Praw[rhi] + mhi;
    float Elo  = __builtin_exp2f(mlo) * S1[rlo];
    float unew = 0.1f * u[index[rlo]] + 0.9f * (Elo - __builtin_exp2f(tplo));

    float Wlo = __builtin_exp2f(mlo) * __builtin_fmaf(mlo, S1[rlo], S2[rlo]);
    float Whi = __builtin_exp2f(mhi) * __builtin_fmaf(mhi, S1[rhi], S2[rhi]);
    float etplo = __builtin_exp2f(tplo);
    float etphi = __builtin_exp2f(tphi);
    float local = (tplo - (Wlo - etplo * tplo) / unew)
                + (tphi - (Whi - etphi * tphi) / unew);
    #pragma unroll
    for (int off = 32; off; off >>= 1) local += __shfl_xor(local, off, 64);
    if (lane == 0) atomicAdd(out, -LN2 * local / (float)NROW);
}

extern "C" void kernel_launch(void* const* d_in, const int* in_sizes, int n_in,
                              void* d_out, int out_size, void* d_ws, size_t ws_size,
                              hipStream_t stream) {
    const int*   index = (const int*)d_in[0];
    const float* feats = (const float*)d_in[1];
    const float* u     = (const float*)d_in[2];
    float* out = (float*)d_out;

    // ws: [S1|S2|Praw|Draw] (4x4096 f32 = 64 KB) | ... | CmF @128KB (2 MB)
    float* S1   = (float*)d_ws;
    float* S2   = S1 + NROW;
    float* Praw = S2 + NROW;
    float* Draw = Praw + NROW;
    short* CmF  = (short*)((char*)d_ws + 131072);

    prep_kernel<<<1024, 256, 0, stream>>>(feats, S1, CmF, out);
    gemm_sym<<<NBLK, 64, 0, stream>>>(CmF, S1, S2, Praw, Draw);
    finalize_kernel<<<32, 64, 0, stream>>>(index, u, S1, S2, Praw, Draw, out);
}

// Round 6
// 111.473 us; speedup vs baseline: 1.0939x; 1.0939x over previous
//
#include <hip/hip_runtime.h>

// BatchIndependentLoss: SupCon-style loss, B=2048, V=2, D=256, N=4096.
// loss = -mean_i( lp_i - (W_i - e^{lp}*lp) / u_new[i%B] )
// R14 == R12 (revert of R13's half-tile regression, +10.7us: the 32-row
// split added +50% L2 fragment traffic and 2x col-path reduction work
// while the occupancy win never materialized -- gemm is per-wave
// latency-bound with depth-2 cover, not wave-starved).
// Best measured config: 111.2us. Window decomposition (stable R10-R13):
// ~88us harness-fixed (256MiB fill ~41us @80% HBM peak + restores +
// graph gaps) + ~23us ours (prep ~3, gemm ~15, finalize ~1, boundaries).
// Structure:
//  - prep: frag-major bf16 pack of the 4096x256 contrast matrix (2 MB,
//    L2-resident), zero S1/S2/out.
//  - gemm: barrier-free symmetric GEMM, one wave = one 64x64 upper-tri
//    tile (2080 single-wave blocks), depth-2 prefetch (3 rotating
//    register buffers), unshifted exp2-domain epilogue: f = exp2(d*C1),
//    S1 += f, S2 += f*d*C1 for row AND col views (one exp2 per element);
//    per-row 2^msd shift is linear and deferred to finalize; msd comes
//    free from diagonal tiles (Draw). Positives only in tiles p == q^32.
//  - finalize: 32 blocks x 64, one wave per band-pair {rows b*64..+63,
//    +2048}; unew per-lane; atomicAdd into out.
// Hard-won negative results (do NOT revisit):
//  - cg::grid.sync @2080 blocks: ~250us/sync on gfx950 (R10).
//  - per-block agent-scope __threadfence: buffer_wbl2+inv per block ->
//    L2 thrash, 340us (R11).
//  - half-tile split for occupancy: +10.7us (R13).
//
// CmF layout: shorts, index = ((band*8 + k)*4 + rt)*512 + (l15*4+quad)*8 + j
// Fragment load for (band, k, rt): wave reads one contiguous 1 KB chunk.

#define BSZ   2048
#define NROW  4096
#define NB64  64                       // 4096/64 bands
#define NT2   (NB64 * (NB64 + 1) / 2)  // 2080 upper-triangle 64x64 tiles
#define C1    (1.4426950408889634f / 0.07f)   // log2(e)/TEMPERATURE
#define LN2   0.6931471805599453f

typedef __attribute__((ext_vector_type(8))) __bf16 bf16x8;
typedef __attribute__((ext_vector_type(4))) float f32x4;

__device__ __forceinline__ short f2bs(float x) {
    __bf16 b = (__bf16)x;
    return __builtin_bit_cast(short, b);
}

// contrast row i = v*B + b  ->  features row b*V + v  (fp32, 256 elems)
__device__ __forceinline__ const float* crow_ptr(const float* feats, int i) {
    return feats + (((i & (BSZ - 1)) * 2 + (i >> 11)) << 8);
}

// ---- pack one gid unit (8 shorts) of the frag-major bf16 operand ----------
__device__ __forceinline__ void pack_unit(const float* __restrict__ feats,
                                          short* __restrict__ CmF, int gid) {
    int quad = gid & 3;
    int l15  = (gid >> 2) & 15;
    int rt   = (gid >> 6) & 3;
    int k    = (gid >> 8) & 7;
    int b    = gid >> 12;
    int srow = (b << 6) + (rt << 4) + l15;
    int kel  = (k << 5) + (quad << 3);
    const float4* fp = (const float4*)(crow_ptr(feats, srow) + kel);
    float4 v0 = fp[0], v1 = fp[1];
    short h[8] = { f2bs(v0.x), f2bs(v0.y), f2bs(v0.z), f2bs(v0.w),
                   f2bs(v1.x), f2bs(v1.y), f2bs(v1.z), f2bs(v1.w) };
    *(int4*)(CmF + gid * 8) = *(int4*)h;
}

// ---------------- prep: pack + zero S1/S2/out ------------------------------
__global__ __launch_bounds__(256) void prep_kernel(const float* __restrict__ feats,
        float* __restrict__ S1, short* __restrict__ CmF, float* __restrict__ out) {
    int gid = blockIdx.x * 256 + threadIdx.x;    // 0..262143
    if (gid < 2 * NROW) S1[gid] = 0.0f;          // S1 | S2 contiguous
    else if (gid == 2 * NROW) out[0] = 0.0f;
    pack_unit(feats, CmF, gid);
}

// ---------------- barrier-free symmetric GEMM + stats ----------------------
// One 64-thread block == one wave == one 64x64 upper-tri tile.
// Depth-2 prefetch (3 rotating buffers). Unshifted exp2 domain.
__global__ __launch_bounds__(64, 2) void gemm_sym(const short* __restrict__ CmF,
        float* __restrict__ S1, float* __restrict__ S2,
        float* __restrict__ Praw, float* __restrict__ Draw) {
    int lane = threadIdx.x;          // 0..63
    int quad = lane >> 4;
    int l15  = lane & 15;

    // triangle decode t -> (p,q), p>=q
    int t = blockIdx.x;
    int p = (int)((sqrtf(8.0f * (float)t + 1.0f) - 1.0f) * 0.5f);
    while ((p + 1) * (p + 2) / 2 <= t) ++p;
    while (p * (p + 1) / 2 > t) --p;
    int q = t - p * (p + 1) / 2;
    int rowBase = q << 6;            // row band (64)
    int colBase = p << 6;            // col band, >= row band
    bool offdiag = (p != q);

    int laneOff = ((l15 << 2) + quad) * 8;
    const short* aB = CmF + q * 16384 + laneOff;
    const short* bB = CmF + p * 16384 + laneOff;

    f32x4 acc[4][4];
    #pragma unroll
    for (int a = 0; a < 4; ++a)
        #pragma unroll
        for (int c = 0; c < 4; ++c) acc[a][c] = (f32x4){0.f, 0.f, 0.f, 0.f};

    // depth-2 software pipeline: 3 rotating fragment buffers
    bf16x8 aF[3][4], bF[3][4];
    #pragma unroll
    for (int rt = 0; rt < 4; ++rt) {
        aF[0][rt] = *(const bf16x8*)(aB + (0 * 4 + rt) * 512);
        bF[0][rt] = *(const bf16x8*)(bB + (0 * 4 + rt) * 512);
    }
    #pragma unroll
    for (int rt = 0; rt < 4; ++rt) {
        aF[1][rt] = *(const bf16x8*)(aB + (1 * 4 + rt) * 512);
        bF[1][rt] = *(const bf16x8*)(bB + (1 * 4 + rt) * 512);
    }

    #pragma unroll
    for (int k = 0; k < 8; ++k) {
        int cur = k % 3;
        int nxt = (k + 2) % 3;
        if (k < 6) {                 // issue loads for step k+2 (2 ahead)
            #pragma unroll
            for (int rt = 0; rt < 4; ++rt) {
                aF[nxt][rt] = *(const bf16x8*)(aB + ((k + 2) * 4 + rt) * 512);
                bF[nxt][rt] = *(const bf16x8*)(bB + ((k + 2) * 4 + rt) * 512);
            }
        }
        __builtin_amdgcn_s_setprio(1);
        #pragma unroll
        for (int rt = 0; rt < 4; ++rt)
            #pragma unroll
            for (int ct = 0; ct < 4; ++ct)
                acc[rt][ct] = __builtin_amdgcn_mfma_f32_16x16x32_bf16(
                    aF[cur][rt], bF[cur][ct], acc[rt][ct], 0, 0, 0);
        __builtin_amdgcn_s_setprio(0);
    }

    // ---- epilogue: C/D layout col = lane&15, row = quad*4 + reg  [m89/m91]
    // Unshifted domain: one exp2 per element, feeds BOTH row and col sums.
    float S1r[4][4] = {}, S2r[4][4] = {};
    float S1c[4] = {}, S2c[4] = {};
    #pragma unroll
    for (int rt = 0; rt < 4; ++rt) {
        #pragma unroll
        for (int ct = 0; ct < 4; ++ct) {
            #pragma unroll
            for (int r = 0; r < 4; ++r) {
                float d  = acc[rt][ct][r];
                float t0 = d * C1;
                float f  = __builtin_exp2f(t0);
                S1r[rt][r] += f;
                S2r[rt][r] = __builtin_fmaf(f, t0, S2r[rt][r]);
                if (offdiag) {
                    S1c[ct] += f;
                    S2c[ct] = __builtin_fmaf(f, t0, S2c[ct]);
                }
            }
        }
    }

    // ---- Praw: only tiles with p == q^32 contain positives (j = i^2048)
    if (p == (q ^ 32) && quad == (l15 >> 2)) {
        int r = l15 & 3;
        #pragma unroll
        for (int rt = 0; rt < 4; ++rt) {
            float t0 = acc[rt][rt][r] * C1;    // positive sits at ct == rt
            Praw[rowBase + rt * 16 + l15] = t0;
            Praw[colBase + rt * 16 + l15] = t0;
        }
    }
    // ---- Draw: diagonal tiles hold the self-dot (msd = -Draw in finalize)
    if (!offdiag && quad == (l15 >> 2)) {
        int r = l15 & 3;
        #pragma unroll
        for (int rt = 0; rt < 4; ++rt)
            Draw[rowBase + rt * 16 + l15] = acc[rt][rt][r] * C1;
    }

    // row-path: reduce over 16 l15 lanes per row, 1-lane atomic per row
    #pragma unroll
    for (int rt = 0; rt < 4; ++rt) {
        #pragma unroll
        for (int r = 0; r < 4; ++r) {
            float e = S1r[rt][r], w = S2r[rt][r];
            #pragma unroll
            for (int off = 1; off < 16; off <<= 1) {
                e += __shfl_xor(e, off, 64);
                w += __shfl_xor(w, off, 64);
            }
            if (l15 == 0) {
                int grow = rowBase + rt * 16 + (quad << 2) + r;
                atomicAdd(&S1[grow], e);
                atomicAdd(&S2[grow], w);
            }
        }
    }
    // col-path: reduce over 4 quads per col, 16-lane atomic
    if (offdiag) {
        #pragma unroll
        for (int ct = 0; ct < 4; ++ct) {
            float e = S1c[ct], w = S2c[ct];
            e += __shfl_xor(e, 16, 64);  w += __shfl_xor(w, 16, 64);
            e += __shfl_xor(e, 32, 64);  w += __shfl_xor(w, 32, 64);
            if (quad == 0) {
                int gcol = colBase + ct * 16 + l15;
                atomicAdd(&S1[gcol], e);
                atomicAdd(&S2[gcol], w);
            }
        }
    }
}

// ---------------- finalize: 32 blocks x 64, one wave per band-pair ---------
// block b owns rows rlo = b*64+lane (batch elems, view 0) and rhi = rlo+2048
// (view 1). unew is per-lane (same batch elem for both rows). m = -Draw;
// E = 2^m*S1; W = 2^m*(S2 + m*S1); tp = Praw + m.
__global__ __launch_bounds__(64) void finalize_kernel(const int* __restrict__ index,
        const float* __restrict__ u, const float* __restrict__ S1,
        const float* __restrict__ S2, const float* __restrict__ Praw,
        const float* __restrict__ Draw, float* __restrict__ out) {
    int lane = threadIdx.x;
    int rlo  = (blockIdx.x << 6) + lane;   // 0..2047
    int rhi  = rlo + BSZ;                  // 2048..4095

    float mlo = -Draw[rlo], mhi = -Draw[rhi];
    float tplo = Praw[rlo] + mlo, tphi = Praw[rhi] + mhi;
    float Elo  = __builtin_exp2f(mlo) * S1[rlo];
    float unew = 0.1f * u[index[rlo]] + 0.9f * (Elo - __builtin_exp2f(tplo));

    float Wlo = __builtin_exp2f(mlo) * __builtin_fmaf(mlo, S1[rlo], S2[rlo]);
    float Whi = __builtin_exp2f(mhi) * __builtin_fmaf(mhi, S1[rhi], S2[rhi]);
    float etplo = __builtin_exp2f(tplo);
    float etphi = __builtin_exp2f(tphi);
    float local = (tplo - (Wlo - etplo * tplo) / unew)
                + (tphi - (Whi - etphi * tphi) / unew);
    #pragma unroll
    for (int off = 32; off; off >>= 1) local += __shfl_xor(local, off, 64);
    if (lane == 0) atomicAdd(out, -LN2 * local / (float)NROW);
}

extern "C" void kernel_launch(void* const* d_in, const int* in_sizes, int n_in,
                              void* d_out, int out_size, void* d_ws, size_t ws_size,
                              hipStream_t stream) {
    const int*   index = (const int*)d_in[0];
    const float* feats = (const float*)d_in[1];
    const float* u     = (const float*)d_in[2];
    float* out = (float*)d_out;

    // ws: [S1|S2|Praw|Draw] (4x4096 f32 = 64 KB) | ... | CmF @128KB (2 MB)
    float* S1   = (float*)d_ws;
    float* S2   = S1 + NROW;
    float* Praw = S2 + NROW;
    float* Draw = Praw + NROW;
    short* CmF  = (short*)((char*)d_ws + 131072);

    prep_kernel<<<1024, 256, 0, stream>>>(feats, S1, CmF, out);
    gemm_sym<<<NT2, 64, 0, stream>>>(CmF, S1, S2, Praw, Draw);
    finalize_kernel<<<32, 64, 0, stream>>>(index, u, S1, S2, Praw, Draw, out);
}